// Round 7
// baseline (227.750 us; speedup 1.0000x reference)
//
#include <hip/hip_runtime.h>
#include <math.h>

#define DEV_INLINE __device__ __forceinline__

// clang-native vector type: required for __builtin_nontemporal_load/store
typedef float v4f __attribute__((ext_vector_type(4)));

// Branch-free fast atan2, Estrin form (dep depth ~20 cyc vs 28 Horner).
// Max error ~1e-5 rad; output sensitivity ~0.07 -> ~1e-6 abs error vs 1.4e-2.
DEV_INLINE float fast_atan2f(float y, float x) {
    const float kPI  = 3.14159265358979323846f;
    const float kPI2 = 1.57079632679489661923f;
    float ax = fabsf(x), ay = fabsf(y);
    float mx = fmaxf(ax, ay);
    float mn = fminf(ax, ay);
    float a  = mn * __builtin_amdgcn_rcpf(mx);
    float s  = a * a;
    float t0 = fmaf(s, -0.01172120f, 0.05265332f);   // c4 + c5 s
    float t1 = fmaf(s, -0.11643287f, 0.19354346f);   // c2 + c3 s
    float t2 = fmaf(s, -0.33262347f, 0.99997726f);   // c0 + c1 s
    float s2 = s * s;
    float u  = fmaf(t0, s2, t1);
    float p  = fmaf(u, s2, t2);
    float r  = a * p;                      // atan(mn/mx) in [0, pi/4]
    r = (ay > ax)   ? (kPI2 - r) : r;
    r = (x < 0.0f)  ? (kPI  - r) : r;
    return copysignf(r, y);
}

// 1 -> 12 -> 1 ReLU MLP, 4-way accumulator tree (crit path 48 -> 20 cyc).
DEV_INLINE float mlp12(float a, const float* __restrict__ w1,
                       const float* __restrict__ b1,
                       const float* __restrict__ w2, float b2) {
    float acc0 = b2, acc1 = 0.0f, acc2 = 0.0f, acc3 = 0.0f;
#pragma unroll
    for (int j = 0; j < 12; j += 4) {
        float h0 = fmaxf(fmaf(a, w1[j + 0], b1[j + 0]), 0.0f);
        float h1 = fmaxf(fmaf(a, w1[j + 1], b1[j + 1]), 0.0f);
        float h2 = fmaxf(fmaf(a, w1[j + 2], b1[j + 2]), 0.0f);
        float h3 = fmaxf(fmaf(a, w1[j + 3], b1[j + 3]), 0.0f);
        acc0 = fmaf(h0, w2[j + 0], acc0);
        acc1 = fmaf(h1, w2[j + 1], acc1);
        acc2 = fmaf(h2, w2[j + 2], acc2);
        acc3 = fmaf(h3, w2[j + 3], acc3);
    }
    return (acc0 + acc1) + (acc2 + acc3);
}

DEV_INLINE void compute_row(float pwm, float theta, float vx0, float vy0,
                            float w0, float pitch,
                            const float* fw1, const float* fb1, const float* fw2, float fb2,
                            const float* rw1, const float* rb1, const float* rw2, float rb2,
                            float rxw, float rxb,
                            float& o0, float& o1, float& o2) {
    const float kLF     = 1.5f;
    const float kLR     = 1.4f;
    const float kCM1    = 550.0f;
    const float kCM2    = 650.0f;
    const float kDT     = 0.01f;
    const float kGRAV   = 9.8f;
    const float kCDRIVE = (float)(3.45 * 0.919 / (0.34 * 1265.0));
    const float kWF     = (float)(1265.0 * 1.5 / 2000.0);  // MASS*LF/IZ
    const float kWR     = (float)(1265.0 * 1.4 / 2000.0);  // MASS*LR/IZ

    const float st = __sinf(theta);
    const float ct = __cosf(theta);
    const float sp = __sinf(pitch);
    const float a_pred = (pwm > 0.0f ? kCM1 : kCM2) * pwm * kCDRIVE;

    o0 = 0.0f; o1 = 0.0f; o2 = 0.0f;
#pragma unroll
    for (int it = 0; it < 2; ++it) {
        const float vx = vx0 + o0;
        const float vy = vy0 + o1;
        const float w  = w0  + o2;

        const float af = theta - fast_atan2f(fmaf(w, kLF, vy), vx);
        const float ar = fast_atan2f(fmaf(w, kLR, -vy), vx);

        const float sf  = af > 0.0f ? 1.0f : -1.0f;
        const float Ffy = sf * mlp12(sf * af, fw1, fb1, fw2, fb2);
        const float sr  = ar > 0.0f ? 1.0f : -1.0f;
        const float Fry = sr * mlp12(sr * ar, rw1, rb1, rw2, rb2);

        const float Frx = fmaf(rxw * vx, vx, a_pred + rxb);

        const float vx_dot = Frx - Ffy * st + vy * w - kGRAV * sp;
        const float vy_dot = Fry + Ffy * ct - vx * w;
        const float w_dot  = kWF * Ffy * ct - kWR * Fry;

        o0 = fmaf(kDT, vx_dot, o0);
        o1 = fmaf(kDT, vy_dot, o1);
        o2 = fmaf(kDT, w_dot,  o2);
    }
}

// Persistent grid-stride kernel with software prefetch: batch k+1's loads are
// issued before batch k's compute, so loads stay in flight during the compute
// phase. NO barrier and NO shared memory in the loop — the output transpose is
// done in-register with __shfl (ds_bpermute), which is race-free by
// construction (the R6 barrier-free LDS transpose was a compiler-visible data
// race and produced garbage).
__global__ __launch_bounds__(256) void dyn_kernel(
    const v4f* __restrict__ x4,
    const float* __restrict__ fy_w1, const float* __restrict__ fy_b1,
    const float* __restrict__ fy_w2, const float* __restrict__ fy_b2,
    const float* __restrict__ ry_w1, const float* __restrict__ ry_b1,
    const float* __restrict__ ry_w2, const float* __restrict__ ry_b2,
    const float* __restrict__ rx_w, const float* __restrict__ rx_b,
    float* __restrict__ out, int nrows, int nbatch) {
    // ---- uniform weights (uniform addresses -> scalar loads) ----
    float fw1[12], fb1[12], fw2[12];
    float rw1[12], rb1[12], rw2[12];
#pragma unroll
    for (int j = 0; j < 12; ++j) {
        fw1[j] = fy_w1[j]; fb1[j] = fy_b1[j]; fw2[j] = fy_w2[j];
        rw1[j] = ry_w1[j]; rb1[j] = ry_b1[j]; rw2[j] = ry_w2[j];
    }
    const float fb2 = fy_b2[0];
    const float rb2 = ry_b2[0];
    const float rxw = rx_w[0];
    const float rxb = rx_b[0];

    const int tid  = threadIdx.x;
    const int wave = tid >> 6;
    const int lane = tid & 63;

    const long long stride = (long long)gridDim.x * 256;  // rows per batch
    const long long gmax   = (long long)nrows * 3;
    long long row = (long long)blockIdx.x * 256 + tid;

    // safe defaults for out-of-range rows: vx0=1 avoids rcp(0) garbage
    v4f lo = {0.f, 0.f, 0.f, 1.f};
    v4f hi = {0.f, 0.f, 0.f, 0.f};
    if (row < nrows) {
        lo = __builtin_nontemporal_load(&x4[2 * row]);
        hi = __builtin_nontemporal_load(&x4[2 * row + 1]);
    }

    for (int k = 0; k < nbatch; ++k) {
        // ---- prefetch batch k+1 (issued before compute; waits at next use) --
        const long long rown = row + stride;
        v4f lon = {0.f, 0.f, 0.f, 1.f};
        v4f hin = {0.f, 0.f, 0.f, 0.f};
        if (k + 1 < nbatch && rown < nrows) {
            lon = __builtin_nontemporal_load(&x4[2 * rown]);
            hin = __builtin_nontemporal_load(&x4[2 * rown + 1]);
        }

        // ---- compute batch k ----
        // layout: lo = {pwm, x1, theta, vx0}, hi = {vy0, w0, x6, pitch}
        float o0, o1, o2;
        compute_row(lo.x, lo.z, lo.w, hi.x, hi.y, hi.w,
                    fw1, fb1, fw2, fb2, rw1, rb1, rw2, rb2, rxw, rxb,
                    o0, o1, o2);

        // ---- in-register wave transpose: this wave's 64 rows form 192
        // contiguous output floats. Position p = j*64+lane maps to source
        // row r=p/3, component c=p%3; fetch via __shfl and store coalesced.
        const long long gbase =
            (k * stride + (long long)blockIdx.x * 256 + wave * 64) * 3;
#pragma unroll
        for (int j = 0; j < 3; ++j) {
            const int p = j * 64 + lane;
            const int r = p / 3;          // magic-mul, ~3 ops
            const int c = p - r * 3;
            const float v0 = __shfl(o0, r, 64);
            const float v1 = __shfl(o1, r, 64);
            const float v2 = __shfl(o2, r, 64);
            const float val = (c == 0) ? v0 : ((c == 1) ? v1 : v2);
            const long long gi = gbase + p;
            if (gi < gmax) __builtin_nontemporal_store(val, &out[gi]);
        }

        row = rown; lo = lon; hi = hin;
    }
}

extern "C" void kernel_launch(void* const* d_in, const int* in_sizes, int n_in,
                              void* d_out, int out_size, void* d_ws, size_t ws_size,
                              hipStream_t stream) {
    const v4f* x4      = (const v4f*)d_in[0];
    const float* fy_w1 = (const float*)d_in[1];
    const float* fy_b1 = (const float*)d_in[2];
    const float* fy_w2 = (const float*)d_in[3];
    const float* fy_b2 = (const float*)d_in[4];
    const float* ry_w1 = (const float*)d_in[5];
    const float* ry_b1 = (const float*)d_in[6];
    const float* ry_w2 = (const float*)d_in[7];
    const float* ry_b2 = (const float*)d_in[8];
    const float* rx_w  = (const float*)d_in[9];
    const float* rx_b  = (const float*)d_in[10];

    const int nrows = in_sizes[0] / 8;
    // 2048 blocks = 8 blocks/CU on 256 CUs; 8 batches/thread at B=4194304.
    int blocks = 2048;
    const int max_blocks = (nrows + 255) / 256;
    if (blocks > max_blocks) blocks = max_blocks;
    const long long stride = (long long)blocks * 256;
    const int nbatch = (int)((nrows + stride - 1) / stride);

    dyn_kernel<<<blocks, 256, 0, stream>>>(
        x4, fy_w1, fy_b1, fy_w2, fy_b2, ry_w1, ry_b1, ry_w2, ry_b2, rx_w, rx_b,
        (float*)d_out, nrows, nbatch);
}